// Round 9
// baseline (646.329 us; speedup 1.0000x reference)
//
#include <hip/hip_runtime.h>
#include <cstdint>

// ---- problem constants ----
constexpr int Bn = 8, Tn = 64, En = 128, Cn = 256;
constexpr int Hn = 512, Mn = 1024, NHd = 8, Dn = 32;
constexpr int NTOK = Bn * Tn * En;          // 65536 tokens
constexpr size_t SZ = (size_t)NTOK * Cn;    // 16,777,216 elements
#define EPSF 1e-5f

typedef __attribute__((ext_vector_type(8))) short short8;
typedef __attribute__((ext_vector_type(4))) float f32x4;

__device__ __forceinline__ float bf2f(unsigned short u) {
  union { unsigned int i; float f; } c; c.i = ((unsigned int)u) << 16; return c.f;
}
__device__ __forceinline__ unsigned short f2bf(float f) {
  union { float f; unsigned int i; } c; c.f = f;
  unsigned int u = c.i;
  return (unsigned short)((u + 0x7fffu + ((u >> 16) & 1u)) >> 16);
}
// tanh-approx GELU, ~7 VALU ops; max abs err ~1e-3, below bf16 rounding in pipe.
__device__ __forceinline__ float gelu_f(float v) {
  float x2 = v * v;
  float p = v * fmaf(x2, 0.10294532f, 2.30221000f);
  float d = 1.0f + __builtin_amdgcn_exp2f(-p);
  return v * __builtin_amdgcn_rcpf(d);
}

// async global->LDS, 16B per lane; lds dest = wave-uniform base + lane*16
__device__ __forceinline__ void gload16(const unsigned short* g, unsigned short* l) {
  __builtin_amdgcn_global_load_lds(
      (const __attribute__((address_space(1))) unsigned int*)g,
      (__attribute__((address_space(3))) unsigned int*)l, 16, 0, 0);
}

#define MEMFENCE() asm volatile("" ::: "memory")

// ---------------- MFMA GEMM: out[M,N] = A[M,K](bf16) @ Bt[N,K]^T (bf16) ------------
// v6 (R6-proven, best of the 2-barrier family): 256x256 tile, BK=32, 8 waves
// 2Mx4N, 4-slot LDS rotation (128 KiB), counted vmcnt(8), swapped mfma so the
// lane owns 4 consecutive N-cols -> vector ushort4/float4 epilogue. scale is
// null-GUARDED. Used for qkv / proj / conv1 / conv2 (fc1+fc2 are fused below).
// EPI: 0 = bf16 plain; 2 = bf16 gelu(acc*scale+bias);
//      3 = f32 2*res + g*(acc*scale+bias); 5 = f32 acc + bias.
// C1A: conv1 A-addressing over t-padded buffer [b][66][e][c], slab = k0>>8.
template <int EPI, bool C1A, int KT, int NT>
__global__ __launch_bounds__(512) void mfma_gemm(
    const unsigned short* __restrict__ A,
    const unsigned short* __restrict__ Bt,
    const float* __restrict__ scale,
    const float* __restrict__ bias,
    const float* __restrict__ resf,
    const float* __restrict__ gscal,
    void* __restrict__ outv) {
  __shared__ unsigned short lds[4][2][8192];   // [slot][A|B][256*32]
  int tid = threadIdx.x;
  int lane = tid & 63, wave = tid >> 6;
  int wr = wave >> 2, wc = wave & 3;           // wave grid 2(M) x 4(N)

  // XCD-aware chunked swizzle (all grids here have nwg % 8 == 0)
  int nwg = gridDim.x * gridDim.y;
  int flat = blockIdx.y * gridDim.x + blockIdx.x;
  int cpx = nwg >> 3;
  int swz = (flat & 7) * cpx + (flat >> 3);
  int ntile = swz % gridDim.x;
  int mtile = swz / gridDim.x;
  int rowBase = mtile * 256;
  int colBase = ntile * 256;
  constexpr int lda = C1A ? 256 : KT;

  int arow = lane & 15, g8 = (lane >> 4) * 8;
  int aoff[8], boff[4];
#pragma unroll
  for (int m = 0; m < 8; ++m) aoff[m] = (wr * 128 + m * 16 + arow) * 32 + g8;
#pragma unroll
  for (int n = 0; n < 4; ++n) boff[n] = (wc * 64 + n * 16 + arow) * 32 + g8;

  f32x4 acc[8][4];
#pragma unroll
  for (int m = 0; m < 8; ++m)
#pragma unroll
    for (int n = 0; n < 4; ++n) acc[m][n] = (f32x4)(0.0f);

  int srow = lane >> 2;          // row within 16-row stage chunk
  int scol = (lane & 3) * 8;     // halfword col within 32-col row

  auto stageA = [&](int T) {
    int k0 = T << 5, slot = T & 3;
#pragma unroll
    for (int r = 0; r < 2; ++r) {
      int row = r * 128 + wave * 16 + srow;
      const unsigned short* src;
      if (C1A) {
        int idx = rowBase + row;
        int bb = idx >> 13, tt = (idx >> 7) & 63, e = idx & 127;
        src = A + ((size_t)((bb * 66 + tt + (k0 >> 8)) * 128 + e)) * 256 +
              (k0 & 255) + scol;
      } else {
        src = A + (size_t)(rowBase + row) * lda + k0 + scol;
      }
      gload16(src, &lds[slot][0][r * 4096 + wave * 512]);
    }
  };
  auto stageB = [&](int T) {
    int k0 = T << 5, slot = T & 3;
#pragma unroll
    for (int r = 0; r < 2; ++r) {
      int row = r * 128 + wave * 16 + srow;
      const unsigned short* src = Bt + (size_t)(colBase + row) * KT + k0 + scol;
      gload16(src, &lds[slot][1][r * 4096 + wave * 512]);
    }
  };

  auto tile = [&](int T, int vm, bool st) {
    if (vm == 8)      asm volatile("s_waitcnt vmcnt(8)" ::: "memory");
    else if (vm == 4) asm volatile("s_waitcnt vmcnt(4)" ::: "memory");
    else              asm volatile("s_waitcnt vmcnt(0)" ::: "memory");
    __builtin_amdgcn_sched_barrier(0);
    __builtin_amdgcn_s_barrier();
    MEMFENCE();
    if (st) stageA(T + 3);
    const unsigned short* as = &lds[T & 3][0][0];
    const unsigned short* bs = &lds[T & 3][1][0];
    short8 bfr[4], af[4];
#pragma unroll
    for (int n = 0; n < 4; ++n) bfr[n] = *(const short8*)(bs + boff[n]);
#pragma unroll
    for (int m = 0; m < 4; ++m) af[m] = *(const short8*)(as + aoff[m]);
    __builtin_amdgcn_s_setprio(1);
#pragma unroll
    for (int m = 0; m < 4; ++m)
#pragma unroll
      for (int n = 0; n < 4; ++n)
        acc[m][n] = __builtin_amdgcn_mfma_f32_16x16x32_bf16(bfr[n], af[m], acc[m][n], 0, 0, 0);
    __builtin_amdgcn_s_setprio(0);
    if (st) stageB(T + 3);
#pragma unroll
    for (int m = 0; m < 4; ++m) af[m] = *(const short8*)(as + aoff[4 + m]);
    __builtin_amdgcn_s_setprio(1);
#pragma unroll
    for (int m = 0; m < 4; ++m)
#pragma unroll
      for (int n = 0; n < 4; ++n)
        acc[4 + m][n] = __builtin_amdgcn_mfma_f32_16x16x32_bf16(bfr[n], af[m], acc[4 + m][n], 0, 0, 0);
    __builtin_amdgcn_s_setprio(0);
  };

  stageA(0); stageB(0); stageA(1); stageB(1); stageA(2); stageB(2);
  constexpr int nkt = KT >> 5;                 // >= 8 for all call sites
#pragma clang loop unroll(disable)
  for (int T = 0; T < nkt - 3; ++T) tile(T, 8, true);
  tile(nkt - 3, 8, false);
  tile(nkt - 2, 4, false);
  tile(nkt - 1, 0, false);
  MEMFENCE();   // keep epilogue loads below the counted-vmcnt region

  // ---- epilogue: lane owns output row (rb + m*16 + cm), cols col..col+3 ----
  int cm = lane & 15;
  int cn0 = (lane >> 4) * 4;
  size_t rb = (size_t)rowBase + wr * 128;
  int cb = colBase + wc * 64;
  float gt = (EPI == 3) ? gscal[0] : 0.f;
  float4 bi4[4], sc4[4];
#pragma unroll
  for (int n = 0; n < 4; ++n) {
    int col = cb + n * 16 + cn0;
    if (EPI != 0) bi4[n] = *(const float4*)(bias + col);
    if (EPI == 2 || EPI == 3) {
      if (scale) sc4[n] = *(const float4*)(scale + col);
      else { sc4[n].x = 1.f; sc4[n].y = 1.f; sc4[n].z = 1.f; sc4[n].w = 1.f; }
    }
  }
#pragma unroll
  for (int m = 0; m < 8; ++m) {
    size_t rowoff = (rb + m * 16 + cm) * (size_t)NT;
#pragma unroll
    for (int n = 0; n < 4; ++n) {
      int col = cb + n * 16 + cn0;
      f32x4 v = acc[m][n];
      if (EPI == 0) {
        ushort4 o = { f2bf(v[0]), f2bf(v[1]), f2bf(v[2]), f2bf(v[3]) };
        *(ushort4*)((unsigned short*)outv + rowoff + col) = o;
      } else if (EPI == 2) {
        ushort4 o = { f2bf(gelu_f(v[0] * sc4[n].x + bi4[n].x)),
                      f2bf(gelu_f(v[1] * sc4[n].y + bi4[n].y)),
                      f2bf(gelu_f(v[2] * sc4[n].z + bi4[n].z)),
                      f2bf(gelu_f(v[3] * sc4[n].w + bi4[n].w)) };
        *(ushort4*)((unsigned short*)outv + rowoff + col) = o;
      } else if (EPI == 3) {
        float4 rf = *(const float4*)(resf + rowoff + col);
        float4 o;
        o.x = 2.0f * rf.x + gt * (v[0] * sc4[n].x + bi4[n].x);
        o.y = 2.0f * rf.y + gt * (v[1] * sc4[n].y + bi4[n].y);
        o.z = 2.0f * rf.z + gt * (v[2] * sc4[n].z + bi4[n].z);
        o.w = 2.0f * rf.w + gt * (v[3] * sc4[n].w + bi4[n].w);
        *(float4*)((float*)outv + rowoff + col) = o;
      } else if (EPI == 5) {
        float4 o;
        o.x = v[0] + bi4[n].x;
        o.y = v[1] + bi4[n].y;
        o.z = v[2] + bi4[n].z;
        o.w = v[3] + bi4[n].w;
        *(float4*)((float*)outv + rowoff + col) = o;
      }
    }
  }
}

// ---------------- fused MLP: O = O + gelu(xm@F1 + b1) @ F2 + b2 --------------------
// Eliminates the 128MB hb write + 128MB read. One block per 256 token rows
// (grid=256). fc1's N=1024 is processed in 8 chunks of 128: GEMM1 (K=256,
// out 256x128) -> gelu+bias -> h_c kept in LDS (bf16, XOR-swizzled
// ((row&7)<<3) so GEMM2's stride-256B fragment reads don't bank-conflict) ->
// GEMM2 partial (K-slice 128) accumulating into persistent acc2[8][4].
// Operands are L2-resident after chunk 0, so the simple 2-slot depth-1 loop
// is latency-adequate here. ds_write'd h_c needs explicit lgkmcnt(0) before
// its visibility barrier (raw s_barrier does not drain LDS writes).
// Swapped mfma(b,a) throughout -> R6-proven lane layout:
//   out[row = base + m*16 + (lane&15)][col = n*16 + (lane>>4)*4 + reg].
__global__ __launch_bounds__(512) void fused_mlp(
    const unsigned short* __restrict__ xm,
    const unsigned short* __restrict__ F1t,
    const float* __restrict__ b1,
    const unsigned short* __restrict__ F2t,
    const float* __restrict__ b2,
    float* __restrict__ O) {
  __shared__ __align__(16) unsigned short g1A[2][8192];   // 256x32, 32 KiB
  __shared__ __align__(16) unsigned short g1B[2][4096];   // 128x32, 16 KiB
  __shared__ __align__(16) unsigned short g2B[2][8192];   // 256x32, 32 KiB
  __shared__ __align__(16) unsigned short hc[32768];      // 256x128, 64 KiB
  int tid = threadIdx.x, lane = tid & 63, wave = tid >> 6;
  int wr = wave >> 2, wc = wave & 3;          // 2(M) x 4(N)
  size_t rowBase = (size_t)blockIdx.x * 256;
  int arow = lane & 15, g8 = (lane >> 4) * 8;
  int srow = lane >> 2, scol = (lane & 3) * 8;
  int cm = lane & 15, cn0 = (lane >> 4) * 4;

  f32x4 acc2[8][4];
#pragma unroll
  for (int m = 0; m < 8; ++m)
#pragma unroll
    for (int n = 0; n < 4; ++n) acc2[m][n] = (f32x4)(0.0f);

  auto stage1A = [&](int t) {                 // xm rows [rowBase, +256), 2 loads
    int k0 = t << 5, slot = t & 1;
#pragma unroll
    for (int r = 0; r < 2; ++r) {
      int row = r * 128 + wave * 16 + srow;
      gload16(xm + (rowBase + row) * 256 + k0 + scol,
              &g1A[slot][r * 4096 + wave * 512]);
    }
  };
  auto stage1B = [&](int t, int c) {          // F1t rows [c*128, +128), 1 load
    int k0 = t << 5, slot = t & 1;
    int row = wave * 16 + srow;
    gload16(F1t + (size_t)(c * 128 + row) * 256 + k0 + scol,
            &g1B[slot][wave * 512]);
  };
  auto stage2B = [&](int kk, int c) {         // F2t all 256 rows, k-slice, 2 loads
    int slot = kk & 1;
#pragma unroll
    for (int r = 0; r < 2; ++r) {
      int row = r * 128 + wave * 16 + srow;
      gload16(F2t + (size_t)row * 1024 + c * 128 + kk * 32 + scol,
              &g2B[slot][r * 4096 + wave * 512]);
    }
  };

#pragma clang loop unroll(disable)
  for (int c = 0; c < 8; ++c) {
    // ---------- GEMM1: h_raw[256x128] = xm @ F1t[c-chunk]^T ----------
    f32x4 acc1[8][2];
#pragma unroll
    for (int m = 0; m < 8; ++m) { acc1[m][0] = (f32x4)(0.0f); acc1[m][1] = (f32x4)(0.0f); }
    stage1A(0); stage1B(0, c);                // 3 loads in flight
#pragma clang loop unroll(disable)
    for (int t = 0; t < 8; ++t) {
      __builtin_amdgcn_s_barrier();           // all waves done reading slot t&1's
      MEMFENCE();                             // previous tenant (t-2)
      if (t < 7) {
        stage1A(t + 1); stage1B(t + 1, c);    // outstanding 6
        asm volatile("s_waitcnt vmcnt(3)" ::: "memory");   // tile t landed
      } else {
        asm volatile("s_waitcnt vmcnt(0)" ::: "memory");
      }
      __builtin_amdgcn_sched_barrier(0);
      __builtin_amdgcn_s_barrier();
      MEMFENCE();
      const unsigned short* as = &g1A[t & 1][0];
      const unsigned short* bs = &g1B[t & 1][0];
      short8 bf[2], af[4];
#pragma unroll
      for (int n = 0; n < 2; ++n)
        bf[n] = *(const short8*)(bs + (wc * 32 + n * 16 + arow) * 32 + g8);
#pragma unroll
      for (int m = 0; m < 4; ++m)
        af[m] = *(const short8*)(as + (wr * 128 + m * 16 + arow) * 32 + g8);
      __builtin_amdgcn_s_setprio(1);
#pragma unroll
      for (int m = 0; m < 4; ++m)
#pragma unroll
        for (int n = 0; n < 2; ++n)
          acc1[m][n] = __builtin_amdgcn_mfma_f32_16x16x32_bf16(bf[n], af[m], acc1[m][n], 0, 0, 0);
      __builtin_amdgcn_s_setprio(0);
#pragma unroll
      for (int m = 0; m < 4; ++m)
        af[m] = *(const short8*)(as + (wr * 128 + (4 + m) * 16 + arow) * 32 + g8);
      __builtin_amdgcn_s_setprio(1);
#pragma unroll
      for (int m = 0; m < 4; ++m)
#pragma unroll
        for (int n = 0; n < 2; ++n)
          acc1[4 + m][n] = __builtin_amdgcn_mfma_f32_16x16x32_bf16(bf[n], af[m], acc1[4 + m][n], 0, 0, 0);
      __builtin_amdgcn_s_setprio(0);
    }
    // ---------- h_c = gelu(h_raw + b1) -> LDS (swizzled) ----------
    // hc overwrite is safe: chunk c-1's GEMM2 reads preceded >=16 barriers.
    float4 b1v[2];
#pragma unroll
    for (int n = 0; n < 2; ++n)
      b1v[n] = *(const float4*)(b1 + c * 128 + wc * 32 + n * 16 + cn0);
#pragma unroll
    for (int m = 0; m < 8; ++m) {
      int hrow = wr * 128 + m * 16 + cm;
#pragma unroll
      for (int n = 0; n < 2; ++n) {
        int hcol = wc * 32 + n * 16 + cn0;
        int eidx = (hrow * 128 + hcol) ^ ((hrow & 7) << 3);
        float4 bv = b1v[n];
        ushort4 hv = { f2bf(gelu_f(acc1[m][n][0] + bv.x)),
                       f2bf(gelu_f(acc1[m][n][1] + bv.y)),
                       f2bf(gelu_f(acc1[m][n][2] + bv.z)),
                       f2bf(gelu_f(acc1[m][n][3] + bv.w)) };
        *(ushort4*)&hc[eidx] = hv;
      }
    }
    asm volatile("s_waitcnt lgkmcnt(0)" ::: "memory");  // drain ds_writes
    __builtin_amdgcn_sched_barrier(0);
    __builtin_amdgcn_s_barrier();             // h_c visible to all waves
    MEMFENCE();
    // ---------- GEMM2 partial: acc2 += h_c @ F2t[:, c-slice]^T ----------
    stage2B(0, c);                            // 2 loads in flight
#pragma clang loop unroll(disable)
    for (int kk = 0; kk < 4; ++kk) {
      __builtin_amdgcn_s_barrier();
      MEMFENCE();
      if (kk < 3) {
        stage2B(kk + 1, c);                   // outstanding 4
        asm volatile("s_waitcnt vmcnt(2)" ::: "memory");
      } else {
        asm volatile("s_waitcnt vmcnt(0)" ::: "memory");
      }
      __builtin_amdgcn_sched_barrier(0);
      __builtin_amdgcn_s_barrier();
      MEMFENCE();
      const unsigned short* bs = &g2B[kk & 1][0];
      short8 bf2[4], af2[4];
#pragma unroll
      for (int n = 0; n < 4; ++n)
        bf2[n] = *(const short8*)(bs + (wc * 64 + n * 16 + arow) * 32 + g8);
#pragma unroll
      for (int m = 0; m < 4; ++m) {
        int row2 = wr * 128 + m * 16 + arow;
        af2[m] = *(const short8*)&hc[(row2 * 128 + kk * 32 + g8) ^ ((row2 & 7) << 3)];
      }
      __builtin_amdgcn_s_setprio(1);
#pragma unroll
      for (int m = 0; m < 4; ++m)
#pragma unroll
        for (int n = 0; n < 4; ++n)
          acc2[m][n] = __builtin_amdgcn_mfma_f32_16x16x32_bf16(bf2[n], af2[m], acc2[m][n], 0, 0, 0);
      __builtin_amdgcn_s_setprio(0);
#pragma unroll
      for (int m = 0; m < 4; ++m) {
        int row2 = wr * 128 + (4 + m) * 16 + arow;
        af2[m] = *(const short8*)&hc[(row2 * 128 + kk * 32 + g8) ^ ((row2 & 7) << 3)];
      }
      __builtin_amdgcn_s_setprio(1);
#pragma unroll
      for (int m = 0; m < 4; ++m)
#pragma unroll
        for (int n = 0; n < 4; ++n)
          acc2[4 + m][n] = __builtin_amdgcn_mfma_f32_16x16x32_bf16(bf2[n], af2[m], acc2[4 + m][n], 0, 0, 0);
      __builtin_amdgcn_s_setprio(0);
    }
  }
  MEMFENCE();
  // ---------- epilogue: O = O + acc2 + b2 (in-place, per-lane disjoint) ----------
  float4 b2v[4];
#pragma unroll
  for (int n = 0; n < 4; ++n)
    b2v[n] = *(const float4*)(b2 + wc * 64 + n * 16 + cn0);
#pragma unroll
  for (int m = 0; m < 8; ++m) {
    size_t rowoff = (rowBase + wr * 128 + m * 16 + cm) * 256;
#pragma unroll
    for (int n = 0; n < 4; ++n) {
      int col = wc * 64 + n * 16 + cn0;
      float4 rf = *(const float4*)(O + rowoff + col);
      f32x4 v = acc2[m][n];
      float4 o;
      o.x = rf.x + v[0] + b2v[n].x;
      o.y = rf.y + v[1] + b2v[n].y;
      o.z = rf.z + v[2] + b2v[n].z;
      o.w = rf.w + v[3] + b2v[n].w;
      *(float4*)(O + rowoff + col) = o;
    }
  }
}

// ---------------- LayerNorm f32 -> bf16, one wave per token ------------------------
template <bool PAD>
__global__ __launch_bounds__(256) void ln256_bf(const float* __restrict__ src,
                                                const float* __restrict__ w,
                                                const float* __restrict__ b,
                                                unsigned short* __restrict__ dst) {
  int lane = threadIdx.x & 63;
  int tok = blockIdx.x * 4 + (threadIdx.x >> 6);
  const float4* row = (const float4*)(src + (size_t)tok * Cn);
  float4 v = row[lane];
  float s  = v.x + v.y + v.z + v.w;
  float s2 = v.x*v.x + v.y*v.y + v.z*v.z + v.w*v.w;
#pragma unroll
  for (int off = 32; off >= 1; off >>= 1) {
    s  += __shfl_xor(s, off, 64);
    s2 += __shfl_xor(s2, off, 64);
  }
  float mean = s * (1.0f / Cn);
  float var = fmaxf(s2 * (1.0f / Cn) - mean * mean, 0.0f);
  float r = rsqrtf(var + EPSF);
  float4 wv = ((const float4*)w)[lane];
  float4 bv = ((const float4*)b)[lane];
  size_t dtok = tok;
  if (PAD) {
    int bb = tok >> 13, tt = (tok >> 7) & 63, e = tok & 127;
    dtok = ((size_t)(bb * 66 + tt + 1)) * 128 + e;
  }
  ushort4 o;
  o.x = f2bf((v.x - mean) * r * wv.x + bv.x);
  o.y = f2bf((v.y - mean) * r * wv.y + bv.y);
  o.z = f2bf((v.z - mean) * r * wv.z + bv.z);
  o.w = f2bf((v.w - mean) * r * wv.w + bv.w);
  *(ushort4*)(dst + dtok * Cn + lane * 4) = o;
}

// ------- fused output-LN + residual1: x1 = x + xs + g * LN(pjo; on_w,on_b) --------
__global__ __launch_bounds__(256) void ln_resid(const float* __restrict__ pjo,
                                                const float* __restrict__ w,
                                                const float* __restrict__ b,
                                                const float* __restrict__ x,
                                                const unsigned short* __restrict__ xs,
                                                const float* __restrict__ gs,
                                                float* __restrict__ x1) {
  int lane = threadIdx.x & 63;
  int tok = blockIdx.x * 4 + (threadIdx.x >> 6);
  size_t base = (size_t)tok * Cn;
  float4 v = ((const float4*)(pjo + base))[lane];
  float s  = v.x + v.y + v.z + v.w;
  float s2 = v.x*v.x + v.y*v.y + v.z*v.z + v.w*v.w;
#pragma unroll
  for (int off = 32; off >= 1; off >>= 1) {
    s  += __shfl_xor(s, off, 64);
    s2 += __shfl_xor(s2, off, 64);
  }
  float mean = s * (1.0f / Cn);
  float var = fmaxf(s2 * (1.0f / Cn) - mean * mean, 0.0f);
  float r = rsqrtf(var + EPSF);
  float4 wv = ((const float4*)w)[lane];
  float4 bv = ((const float4*)b)[lane];
  float g = gs[0];
  float4 xv = ((const float4*)(x + base))[lane];
  ushort4 s4 = ((const ushort4*)(xs + base))[lane];
  float4 o;
  o.x = xv.x + bf2f(s4.x) + g * ((v.x - mean) * r * wv.x + bv.x);
  o.y = xv.y + bf2f(s4.y) + g * ((v.y - mean) * r * wv.y + bv.y);
  o.z = xv.z + bf2f(s4.z) + g * ((v.z - mean) * r * wv.z + bv.z);
  o.w = xv.w + bf2f(s4.w) + g * ((v.w - mean) * r * wv.w + bv.w);
  ((float4*)(x1 + base))[lane] = o;
}

// ---------------- MFMA spatial attention, one block per (frame, head) --------------
__global__ __launch_bounds__(256) void attn_mfma(const unsigned short* __restrict__ qkv,
                                                 const float* __restrict__ maskh,
                                                 unsigned short* __restrict__ o) {
  __shared__ unsigned short Qs[128 * 32];
  __shared__ unsigned short Ks[128 * 32];
  __shared__ unsigned short Vt[32 * 136];    // [d][f], padded
  __shared__ unsigned short Ps[128 * 136];   // [e][f], padded
  int tid = threadIdx.x, lane = tid & 63, wave = tid >> 6;
  int h = blockIdx.x & 7, bt = blockIdx.x >> 3;
  size_t gbase = (size_t)bt * 128 * 768 + h * 32;
#pragma unroll
  for (int i = 0; i < 2; ++i) {
    int q = wave * 2 + i;
    int row = q * 16 + (lane >> 2);
    int seg = (lane & 3) * 8;
    gload16(qkv + gbase + (size_t)row * 768 + seg, &Qs[q * 512]);
    gload16(qkv + gbase + 256 + (size_t)row * 768 + seg, &Ks[q * 512]);
  }
  {
    int e = tid >> 1, dh = (tid & 1) * 16;
    const unsigned short* gv = qkv + gbase + 512 + (size_t)e * 768 + dh;
    short8 v0 = *(const short8*)gv;
    short8 v1 = *(const short8*)(gv + 8);
#pragma unroll
    for (int j = 0; j < 8; ++j) {
      Vt[(dh + j) * 136 + e]     = (unsigned short)v0[j];
      Vt[(dh + 8 + j) * 136 + e] = (unsigned short)v1[j];
    }
  }
  __syncthreads();
  int arow = lane & 15, akk = (lane >> 4) * 8;
  int crow0 = (lane >> 4) * 4, ccol = lane & 15;
  short8 af0 = *(const short8*)&Qs[(wave * 32 + arow) * 32 + akk];
  short8 af1 = *(const short8*)&Qs[(wave * 32 + 16 + arow) * 32 + akk];
#pragma unroll
  for (int j = 0; j < 8; ++j) {
    short8 bfr = *(const short8*)&Ks[(j * 16 + arow) * 32 + akk];
    f32x4 s0 = __builtin_amdgcn_mfma_f32_16x16x32_bf16(af0, bfr, (f32x4)(0.0f), 0, 0, 0);
    f32x4 s1 = __builtin_amdgcn_mfma_f32_16x16x32_bf16(af1, bfr, (f32x4)(0.0f), 0, 0, 0);
    int f = j * 16 + ccol;
#pragma unroll
    for (int r = 0; r < 4; ++r) {
      int e0 = wave * 32 + crow0 + r;
      int e1 = e0 + 16;
      Ps[e0 * 136 + f] = f2bf(maskh[e0 * 128 + f] * s0[r] + 0.5f);
      Ps[e1 * 136 + f] = f2bf(maskh[e1 * 128 + f] * s1[r] + 0.5f);
    }
  }
  f32x4 acc[2][2];
#pragma unroll
  for (int i = 0; i < 2; ++i)
#pragma unroll
    for (int j = 0; j < 2; ++j) acc[i][j] = (f32x4)(0.0f);
#pragma unroll
  for (int k0 = 0; k0 < 128; k0 += 32) {
    short8 a0 = *(const short8*)&Ps[(wave * 32 + arow) * 136 + k0 + akk];
    short8 a1 = *(const short8*)&Ps[(wave * 32 + 16 + arow) * 136 + k0 + akk];
    short8 b0 = *(const short8*)&Vt[arow * 136 + k0 + akk];
    short8 b1 = *(const short8*)&Vt[(16 + arow) * 136 + k0 + akk];
    acc[0][0] = __builtin_amdgcn_mfma_f32_16x16x32_bf16(a0, b0, acc[0][0], 0, 0, 0);
    acc[0][1] = __builtin_amdgcn_mfma_f32_16x16x32_bf16(a0, b1, acc[0][1], 0, 0, 0);
    acc[1][0] = __builtin_amdgcn_mfma_f32_16x16x32_bf16(a1, b0, acc[1][0], 0, 0, 0);
    acc[1][1] = __builtin_amdgcn_mfma_f32_16x16x32_bf16(a1, b1, acc[1][1], 0, 0, 0);
  }
  unsigned short* ob = o + (size_t)bt * 128 * 256 + h * 32;
#pragma unroll
  for (int i = 0; i < 2; ++i)
#pragma unroll
    for (int j = 0; j < 2; ++j)
#pragma unroll
      for (int r = 0; r < 4; ++r) {
        int e = wave * 32 + i * 16 + crow0 + r;
        ob[(size_t)e * 256 + j * 16 + ccol] = f2bf(acc[i][j][r]);
      }
}

// ---------------- prep kernels -----------------------------------------------------
__global__ __launch_bounds__(256) void transcast(const float* __restrict__ src,
                                                 unsigned short* __restrict__ dst,
                                                 int N, int K) {   // dst[n*K+k] = src[k*N+n]
  int idx = blockIdx.x * 256 + threadIdx.x;
  int n = idx / K, k = idx - n * K;
  dst[idx] = f2bf(src[(size_t)k * N + n]);
}
__global__ __launch_bounds__(256) void castbf(const float* __restrict__ s,
                                              unsigned short* __restrict__ d) {
  int i = blockIdx.x * 256 + threadIdx.x;
  d[i] = f2bf(s[i]);
}
__global__ __launch_bounds__(256) void pack_conv1(const float* __restrict__ w1,
                                                  unsigned short* __restrict__ dst) {
  int idx = blockIdx.x * 256 + threadIdx.x;   // 512*768: [h][slab*256+c]
  int hh = idx / 768, kk = idx - hh * 768;
  int slab = kk >> 8, c = kk & 255;
  dst[idx] = f2bf(w1[(size_t)hh * 768 + c * 3 + slab]);
}
__global__ __launch_bounds__(256) void bnfold(const float* __restrict__ w,
                                              const float* __restrict__ bvec,
                                              const float* __restrict__ m,
                                              const float* __restrict__ v,
                                              float* __restrict__ s,
                                              float* __restrict__ o, int n) {
  int i = blockIdx.x * 256 + threadIdx.x;
  if (i < n) {
    float sc = w[i] * rsqrtf(v[i] + EPSF);
    s[i] = sc;
    o[i] = bvec[i] - m[i] * sc;
  }
}
__global__ __launch_bounds__(256) void mask_prep(const int* __restrict__ adj,
                                                 float* __restrict__ maskh) {
  int i = blockIdx.x * 256 + threadIdx.x;   // 16384
  maskh[i] = 0.5f * (float)adj[i];
}
__global__ __launch_bounds__(256) void zero_pad(unsigned short* __restrict__ xt) {
  int idx = blockIdx.x * 256 + threadIdx.x;   // 8 b * 2 rows * 128*256
  int bb = idx >> 16;
  int rem = idx & 65535;
  int which = rem >> 15;      // 0 -> t_pad 0, 1 -> t_pad 65
  int off = rem & 32767;
  size_t base = ((size_t)(bb * 66 + which * 65)) * 128 * 256;
  xt[base + off] = 0;
}

// ---------------- host-side launch --------------------------------------------------
extern "C" void kernel_launch(void* const* d_in, const int* in_sizes, int n_in,
                              void* d_out, int out_size, void* d_ws, size_t ws_size,
                              hipStream_t stream) {
  (void)in_sizes; (void)n_in; (void)out_size; (void)ws_size;
  const float* x       = (const float*)d_in[0];
  const int*   adj     = (const int*)  d_in[1];
  const float* n1_w    = (const float*)d_in[2];
  const float* n1_b    = (const float*)d_in[3];
  const float* q_w     = (const float*)d_in[4];
  const float* k_w     = (const float*)d_in[5];
  const float* v_w     = (const float*)d_in[6];
  const float* proj_w  = (const float*)d_in[7];
  const float* proj_b  = (const float*)d_in[8];
  const float* on_w    = (const float*)d_in[9];
  const float* on_b    = (const float*)d_in[10];
  const float* gamma_s = (const float*)d_in[11];
  const float* conv1_w = (const float*)d_in[12];
  const float* bn1_w   = (const float*)d_in[13];
  const float* bn1_b   = (const float*)d_in[14];
  const float* bn1_m   = (const float*)d_in[15];
  const float* bn1_v   = (const float*)d_in[16];
  const float* conv2_w = (const float*)d_in[17];
  const float* bn2_w   = (const float*)d_in[18];
  const float* bn2_b   = (const float*)d_in[19];
  const float* bn2_m   = (const float*)d_in[20];
  const float* bn2_v   = (const float*)d_in[21];
  const float* tn_w    = (const float*)d_in[22];
  const float* tn_b    = (const float*)d_in[23];
  const float* gamma_t = (const float*)d_in[24];
  const float* n3_w    = (const float*)d_in[25];
  const float* n3_b    = (const float*)d_in[26];
  const float* fc1_w   = (const float*)d_in[27];
  const float* fc1_b   = (const float*)d_in[28];
  const float* fc2_w   = (const float*)d_in[29];
  const float* fc2_b   = (const float*)d_in[30];
  float* O = (float*)d_out;

  const size_t MB = 1024 * 1024;
  char* wsb = (char*)d_ws;
  // live-range overlaid buffers
  unsigned short* qkvb = (unsigned short*)(wsb + 0);        // 96 MB  [qkv gemm -> attn]
  float*          pjo  = (float*)(wsb + 0);                 // 64 MB  [proj out f32]
  float*          x1b  = (float*)(wsb + 0);                 // 64 MB  [ln_resid -> conv2] (aliases pjo, in-place)
  unsigned short* xmb  = (unsigned short*)(wsb + 0);        // 32 MB  [ln3 -> fused_mlp]
  unsigned short* xtp  = (unsigned short*)(wsb + 64 * MB);  // 33 MB  [ln_t -> conv1]
  unsigned short* xsb  = (unsigned short*)(wsb + 96 * MB);  // 32 MB  [ln1 -> ln_resid]
  unsigned short* oat  = (unsigned short*)(wsb + 128 * MB); // 32 MB  [attn -> proj]
  unsigned short* y1b  = (unsigned short*)(wsb + 100 * MB); // 64 MB  [conv1 -> conv2]
  char* wp = wsb + 164 * MB;
  unsigned short* Wqkv = (unsigned short*)wp;  wp += 768 * 256 * 2;
  unsigned short* PjT  = (unsigned short*)wp;  wp += 256 * 256 * 2;
  unsigned short* W1t  = (unsigned short*)wp;  wp += 512 * 768 * 2;
  unsigned short* W2t  = (unsigned short*)wp;  wp += 256 * 512 * 2;
  unsigned short* F1t  = (unsigned short*)wp;  wp += 1024 * 256 * 2;
  unsigned short* F2t  = (unsigned short*)wp;  wp += 256 * 1024 * 2;
  float* s1 = (float*)wp; wp += 512 * 4;
  float* o1 = (float*)wp; wp += 512 * 4;
  float* s2 = (float*)wp; wp += 256 * 4;
  float* o2 = (float*)wp; wp += 256 * 4;
  float* maskh = (float*)wp; wp += 16384 * 4;

  // ---- prep (cheap, once per launch) ----
  transcast<<<768 * 256 / 256, 256, 0, stream>>>(q_w, Wqkv, 256, 256);
  transcast<<<768 * 256 / 256, 256, 0, stream>>>(k_w, Wqkv + 256 * 256, 256, 256);
  transcast<<<768 * 256 / 256, 256, 0, stream>>>(v_w, Wqkv + 512 * 256, 256, 256);
  transcast<<<256 * 256 / 256, 256, 0, stream>>>(proj_w, PjT, 256, 256);
  pack_conv1<<<512 * 768 / 256, 256, 0, stream>>>(conv1_w, W1t);
  castbf<<<256 * 512 / 256, 256, 0, stream>>>(conv2_w, W2t);   // already [C][H] = [N][K]
  transcast<<<1024 * 256 / 256, 256, 0, stream>>>(fc1_w, F1t, 1024, 256);
  transcast<<<256 * 1024 / 256, 256, 0, stream>>>(fc2_w, F2t, 256, 1024);
  bnfold<<<2, 256, 0, stream>>>(bn1_w, bn1_b, bn1_m, bn1_v, s1, o1, 512);
  bnfold<<<1, 256, 0, stream>>>(bn2_w, bn2_b, bn2_m, bn2_v, s2, o2, 256);
  mask_prep<<<64, 256, 0, stream>>>(adj, maskh);
  zero_pad<<<524288 / 256, 256, 0, stream>>>(xtp);

  // ---- spatial attention branch ----
  ln256_bf<false><<<NTOK / 4, 256, 0, stream>>>(x, n1_w, n1_b, xsb);
  mfma_gemm<0, false, 256, 768><<<dim3(3, 256), 512, 0, stream>>>(xsb, Wqkv, nullptr, nullptr, nullptr, nullptr, qkvb);
  attn_mfma<<<Bn * Tn * NHd, 256, 0, stream>>>(qkvb, maskh, oat);
  mfma_gemm<5, false, 256, 256><<<dim3(1, 256), 512, 0, stream>>>(oat, PjT, nullptr, proj_b, nullptr, nullptr, pjo);
  ln_resid<<<NTOK / 4, 256, 0, stream>>>(pjo, on_w, on_b, x, xsb, gamma_s, x1b);

  // ---- temporal conv branch ----
  ln256_bf<true><<<NTOK / 4, 256, 0, stream>>>(x1b, tn_w, tn_b, xtp);
  mfma_gemm<2, true, 768, 512><<<dim3(2, 256), 512, 0, stream>>>(xtp, W1t, s1, o1, nullptr, nullptr, y1b);
  mfma_gemm<3, false, 512, 256><<<dim3(1, 256), 512, 0, stream>>>(y1b, W2t, s2, o2, x1b, gamma_t, O);

  // ---- MLP (fc1+fc2 fused; eliminates the 128MB hb write + 128MB read) ----
  ln256_bf<false><<<NTOK / 4, 256, 0, stream>>>(O, n3_w, n3_b, xmb);
  fused_mlp<<<256, 512, 0, stream>>>(xmb, F1t, fc1_b, F2t, fc2_b, O);
}

// Round 10
// 607.807 us; speedup vs baseline: 1.0634x; 1.0634x over previous
//
#include <hip/hip_runtime.h>
#include <cstdint>

// ---- problem constants ----
constexpr int Bn = 8, Tn = 64, En = 128, Cn = 256;
constexpr int Hn = 512, Mn = 1024, NHd = 8, Dn = 32;
constexpr int NTOK = Bn * Tn * En;          // 65536 tokens
constexpr size_t SZ = (size_t)NTOK * Cn;    // 16,777,216 elements
#define EPSF 1e-5f

typedef __attribute__((ext_vector_type(8))) short short8;
typedef __attribute__((ext_vector_type(4))) float f32x4;

__device__ __forceinline__ float bf2f(unsigned short u) {
  union { unsigned int i; float f; } c; c.i = ((unsigned int)u) << 16; return c.f;
}
__device__ __forceinline__ unsigned short f2bf(float f) {
  union { float f; unsigned int i; } c; c.f = f;
  unsigned int u = c.i;
  return (unsigned short)((u + 0x7fffu + ((u >> 16) & 1u)) >> 16);
}
// tanh-approx GELU, ~7 VALU ops; max abs err ~1e-3, below bf16 rounding in pipe.
__device__ __forceinline__ float gelu_f(float v) {
  float x2 = v * v;
  float p = v * fmaf(x2, 0.10294532f, 2.30221000f);
  float d = 1.0f + __builtin_amdgcn_exp2f(-p);
  return v * __builtin_amdgcn_rcpf(d);
}

// async global->LDS, 16B per lane; lds dest = wave-uniform base + lane*16
__device__ __forceinline__ void gload16(const unsigned short* g, unsigned short* l) {
  __builtin_amdgcn_global_load_lds(
      (const __attribute__((address_space(1))) unsigned int*)g,
      (__attribute__((address_space(3))) unsigned int*)l, 16, 0, 0);
}

#define MEMFENCE() asm volatile("" ::: "memory")

// ---------------- MFMA GEMM: out[M,N] = A[M,K](bf16) @ Bt[N,K]^T (bf16) ------------
// v9 = v6 (4-slot, counted vmcnt(8), swapped-mfma vector epilogue) +
//  (a) T2 XOR-swizzle: LDS rows are 64B; a wave's b128 fragment reads were
//      8-way bank-conflicted (16 lanes, same col-byte, rows mod 2 -> 2 bank-
//      quads x 8 lanes; SQ_LDS_BANK_CONFLICT ~3-5M/dispatch). Swizzle
//      hw ^= ((row&8)?16:0) applied BOTH on the stage's global source column
//      and on the fragment-read offset (both-sides-or-neither) -> 4-way.
//  (b) per-phase structure (T3-like): each K-tile = 2 phases of
//      {ds_read quadrant || stage half(T+3); lgkmcnt(0); sched_barrier;
//       s_barrier; setprio(1) 16 MFMA setprio(0); s_barrier}.
//      Single counted vmcnt(8) per K-tile (depth-3 unchanged). Slot-safety:
//      reads of slot s complete (lgkmcnt(0)) before the barrier preceding
//      any write of s (stage of tile T writes slot (T-1)&3, after barrier#1
//      which follows tile T-1's completed, drained reads).
// EPI: 0 = bf16 plain; 2 = bf16 gelu(acc*scale+bias);
//      3 = f32 2*res + g*(acc*scale+bias); 4 = f32 res + acc + bias;
//      5 = f32 acc + bias.   scale is null-GUARDED (fc1: EPI2, scale=null).
// C1A: conv1 A-addressing over t-padded buffer [b][66][e][c], slab = k0>>8.
template <int EPI, bool C1A, int KT, int NT>
__global__ __launch_bounds__(512) void mfma_gemm(
    const unsigned short* __restrict__ A,
    const unsigned short* __restrict__ Bt,
    const float* __restrict__ scale,
    const float* __restrict__ bias,
    const float* __restrict__ resf,
    const float* __restrict__ gscal,
    void* __restrict__ outv) {
  __shared__ unsigned short lds[4][2][8192];   // [slot][A|B][256*32]
  int tid = threadIdx.x;
  int lane = tid & 63, wave = tid >> 6;
  int wr = wave >> 2, wc = wave & 3;           // wave grid 2(M) x 4(N)

  // XCD-aware chunked swizzle (all grids here have nwg % 8 == 0)
  int nwg = gridDim.x * gridDim.y;
  int flat = blockIdx.y * gridDim.x + blockIdx.x;
  int cpx = nwg >> 3;
  int swz = (flat & 7) * cpx + (flat >> 3);
  int ntile = swz % gridDim.x;
  int mtile = swz / gridDim.x;
  int rowBase = mtile * 256;
  int colBase = ntile * 256;
  constexpr int lda = C1A ? 256 : KT;

  // fragment LDS offsets (halfword units), T2-swizzled: hw = g8 ^ ((arow&8)<<1)
  int arow = lane & 15;
  int g8s = ((lane >> 4) * 8) ^ ((arow & 8) << 1);
  int aoff[8], boff[4];
#pragma unroll
  for (int m = 0; m < 8; ++m) aoff[m] = (wr * 128 + m * 16 + arow) * 32 + g8s;
#pragma unroll
  for (int n = 0; n < 4; ++n) boff[n] = (wc * 64 + n * 16 + arow) * 32 + g8s;

  f32x4 acc[8][4];
#pragma unroll
  for (int m = 0; m < 8; ++m)
#pragma unroll
    for (int n = 0; n < 4; ++n) acc[m][n] = (f32x4)(0.0f);

  int srow = lane >> 2;                        // row within 16-row stage chunk
  int scol = ((lane & 3) * 8) ^ ((srow & 8) << 1);  // T2 pre-swizzled source col

  auto stageA = [&](int T) {
    int k0 = T << 5, slot = T & 3;
#pragma unroll
    for (int r = 0; r < 2; ++r) {
      int row = r * 128 + wave * 16 + srow;
      const unsigned short* src;
      if (C1A) {
        int idx = rowBase + row;
        int bb = idx >> 13, tt = (idx >> 7) & 63, e = idx & 127;
        src = A + ((size_t)((bb * 66 + tt + (k0 >> 8)) * 128 + e)) * 256 +
              (k0 & 255) + scol;
      } else {
        src = A + (size_t)(rowBase + row) * lda + k0 + scol;
      }
      gload16(src, &lds[slot][0][r * 4096 + wave * 512]);
    }
  };
  auto stageB = [&](int T) {
    int k0 = T << 5, slot = T & 3;
#pragma unroll
    for (int r = 0; r < 2; ++r) {
      int row = r * 128 + wave * 16 + srow;
      const unsigned short* src = Bt + (size_t)(colBase + row) * KT + k0 + scol;
      gload16(src, &lds[slot][1][r * 4096 + wave * 512]);
    }
  };

  // one K-tile: vmcnt gate -> 2 phases, each {ds_read || stage; lgkm0; bar;
  // 16 MFMA; bar}. Swapped mfma(bfr,af): lane owns 4 consecutive N-cols.
  auto tile = [&](int T, int vm, bool st) {
    if (vm == 8)      asm volatile("s_waitcnt vmcnt(8)" ::: "memory");
    else if (vm == 4) asm volatile("s_waitcnt vmcnt(4)" ::: "memory");
    else              asm volatile("s_waitcnt vmcnt(0)" ::: "memory");
    __builtin_amdgcn_sched_barrier(0);
    __builtin_amdgcn_s_barrier();              // #1: tile T visible; slot (T-1)&3 free
    MEMFENCE();
    const unsigned short* as = &lds[T & 3][0][0];
    const unsigned short* bs = &lds[T & 3][1][0];
    short8 bfr[4], af[4];
    // ---- phase 1: quadrant m0-3 ----
#pragma unroll
    for (int n = 0; n < 4; ++n) bfr[n] = *(const short8*)(bs + boff[n]);
#pragma unroll
    for (int m = 0; m < 4; ++m) af[m] = *(const short8*)(as + aoff[m]);
    if (st) stageA(T + 3);
    asm volatile("s_waitcnt lgkmcnt(0)" ::: "memory");
    __builtin_amdgcn_sched_barrier(0);
    __builtin_amdgcn_s_barrier();              // #2
    __builtin_amdgcn_s_setprio(1);
#pragma unroll
    for (int m = 0; m < 4; ++m)
#pragma unroll
      for (int n = 0; n < 4; ++n)
        acc[m][n] = __builtin_amdgcn_mfma_f32_16x16x32_bf16(bfr[n], af[m], acc[m][n], 0, 0, 0);
    __builtin_amdgcn_s_setprio(0);
    // ---- phase 2: quadrant m4-7 ----
    __builtin_amdgcn_s_barrier();              // #3
#pragma unroll
    for (int m = 0; m < 4; ++m) af[m] = *(const short8*)(as + aoff[4 + m]);
    if (st) stageB(T + 3);
    asm volatile("s_waitcnt lgkmcnt(0)" ::: "memory");
    __builtin_amdgcn_sched_barrier(0);
    __builtin_amdgcn_s_barrier();              // #4
    __builtin_amdgcn_s_setprio(1);
#pragma unroll
    for (int m = 0; m < 4; ++m)
#pragma unroll
      for (int n = 0; n < 4; ++n)
        acc[4 + m][n] = __builtin_amdgcn_mfma_f32_16x16x32_bf16(bfr[n], af[m], acc[4 + m][n], 0, 0, 0);
    __builtin_amdgcn_s_setprio(0);
  };

  stageA(0); stageB(0); stageA(1); stageB(1); stageA(2); stageB(2);
  constexpr int nkt = KT >> 5;                 // >= 8 for all call sites
#pragma clang loop unroll(disable)
  for (int T = 0; T < nkt - 3; ++T) tile(T, 8, true);
  tile(nkt - 3, 8, false);
  tile(nkt - 2, 4, false);
  tile(nkt - 1, 0, false);
  MEMFENCE();   // keep epilogue loads below the counted-vmcnt region

  // ---- epilogue: lane owns output row (rb + m*16 + cm), cols col..col+3 ----
  int cm = lane & 15;
  int cn0 = (lane >> 4) * 4;
  size_t rb = (size_t)rowBase + wr * 128;
  int cb = colBase + wc * 64;
  float gt = (EPI == 3) ? gscal[0] : 0.f;
  float4 bi4[4], sc4[4];
#pragma unroll
  for (int n = 0; n < 4; ++n) {
    int col = cb + n * 16 + cn0;
    if (EPI != 0) bi4[n] = *(const float4*)(bias + col);
    if (EPI == 2 || EPI == 3) {
      if (scale) sc4[n] = *(const float4*)(scale + col);
      else { sc4[n].x = 1.f; sc4[n].y = 1.f; sc4[n].z = 1.f; sc4[n].w = 1.f; }
    }
  }
#pragma unroll
  for (int m = 0; m < 8; ++m) {
    size_t rowoff = (rb + m * 16 + cm) * (size_t)NT;
#pragma unroll
    for (int n = 0; n < 4; ++n) {
      int col = cb + n * 16 + cn0;
      f32x4 v = acc[m][n];
      if (EPI == 0) {
        ushort4 o = { f2bf(v[0]), f2bf(v[1]), f2bf(v[2]), f2bf(v[3]) };
        *(ushort4*)((unsigned short*)outv + rowoff + col) = o;
      } else if (EPI == 2) {
        ushort4 o = { f2bf(gelu_f(v[0] * sc4[n].x + bi4[n].x)),
                      f2bf(gelu_f(v[1] * sc4[n].y + bi4[n].y)),
                      f2bf(gelu_f(v[2] * sc4[n].z + bi4[n].z)),
                      f2bf(gelu_f(v[3] * sc4[n].w + bi4[n].w)) };
        *(ushort4*)((unsigned short*)outv + rowoff + col) = o;
      } else if (EPI == 3) {
        float4 rf = *(const float4*)(resf + rowoff + col);
        float4 o;
        o.x = 2.0f * rf.x + gt * (v[0] * sc4[n].x + bi4[n].x);
        o.y = 2.0f * rf.y + gt * (v[1] * sc4[n].y + bi4[n].y);
        o.z = 2.0f * rf.z + gt * (v[2] * sc4[n].z + bi4[n].z);
        o.w = 2.0f * rf.w + gt * (v[3] * sc4[n].w + bi4[n].w);
        *(float4*)((float*)outv + rowoff + col) = o;
      } else if (EPI == 4) {
        float4 rf = *(const float4*)(resf + rowoff + col);
        float4 o;
        o.x = rf.x + v[0] + bi4[n].x;
        o.y = rf.y + v[1] + bi4[n].y;
        o.z = rf.z + v[2] + bi4[n].z;
        o.w = rf.w + v[3] + bi4[n].w;
        *(float4*)((float*)outv + rowoff + col) = o;
      } else if (EPI == 5) {
        float4 o;
        o.x = v[0] + bi4[n].x;
        o.y = v[1] + bi4[n].y;
        o.z = v[2] + bi4[n].z;
        o.w = v[3] + bi4[n].w;
        *(float4*)((float*)outv + rowoff + col) = o;
      }
    }
  }
}

// ---------------- LayerNorm f32 -> bf16, one wave per token ------------------------
template <bool PAD>
__global__ __launch_bounds__(256) void ln256_bf(const float* __restrict__ src,
                                                const float* __restrict__ w,
                                                const float* __restrict__ b,
                                                unsigned short* __restrict__ dst) {
  int lane = threadIdx.x & 63;
  int tok = blockIdx.x * 4 + (threadIdx.x >> 6);
  const float4* row = (const float4*)(src + (size_t)tok * Cn);
  float4 v = row[lane];
  float s  = v.x + v.y + v.z + v.w;
  float s2 = v.x*v.x + v.y*v.y + v.z*v.z + v.w*v.w;
#pragma unroll
  for (int off = 32; off >= 1; off >>= 1) {
    s  += __shfl_xor(s, off, 64);
    s2 += __shfl_xor(s2, off, 64);
  }
  float mean = s * (1.0f / Cn);
  float var = fmaxf(s2 * (1.0f / Cn) - mean * mean, 0.0f);
  float r = rsqrtf(var + EPSF);
  float4 wv = ((const float4*)w)[lane];
  float4 bv = ((const float4*)b)[lane];
  size_t dtok = tok;
  if (PAD) {
    int bb = tok >> 13, tt = (tok >> 7) & 63, e = tok & 127;
    dtok = ((size_t)(bb * 66 + tt + 1)) * 128 + e;
  }
  ushort4 o;
  o.x = f2bf((v.x - mean) * r * wv.x + bv.x);
  o.y = f2bf((v.y - mean) * r * wv.y + bv.y);
  o.z = f2bf((v.z - mean) * r * wv.z + bv.z);
  o.w = f2bf((v.w - mean) * r * wv.w + bv.w);
  *(ushort4*)(dst + dtok * Cn + lane * 4) = o;
}

// ------- fused output-LN + residual1: x1 = x + xs + g * LN(pjo; on_w,on_b) --------
__global__ __launch_bounds__(256) void ln_resid(const float* __restrict__ pjo,
                                                const float* __restrict__ w,
                                                const float* __restrict__ b,
                                                const float* __restrict__ x,
                                                const unsigned short* __restrict__ xs,
                                                const float* __restrict__ gs,
                                                float* __restrict__ x1) {
  int lane = threadIdx.x & 63;
  int tok = blockIdx.x * 4 + (threadIdx.x >> 6);
  size_t base = (size_t)tok * Cn;
  float4 v = ((const float4*)(pjo + base))[lane];
  float s  = v.x + v.y + v.z + v.w;
  float s2 = v.x*v.x + v.y*v.y + v.z*v.z + v.w*v.w;
#pragma unroll
  for (int off = 32; off >= 1; off >>= 1) {
    s  += __shfl_xor(s, off, 64);
    s2 += __shfl_xor(s2, off, 64);
  }
  float mean = s * (1.0f / Cn);
  float var = fmaxf(s2 * (1.0f / Cn) - mean * mean, 0.0f);
  float r = rsqrtf(var + EPSF);
  float4 wv = ((const float4*)w)[lane];
  float4 bv = ((const float4*)b)[lane];
  float g = gs[0];
  float4 xv = ((const float4*)(x + base))[lane];
  ushort4 s4 = ((const ushort4*)(xs + base))[lane];
  float4 o;
  o.x = xv.x + bf2f(s4.x) + g * ((v.x - mean) * r * wv.x + bv.x);
  o.y = xv.y + bf2f(s4.y) + g * ((v.y - mean) * r * wv.y + bv.y);
  o.z = xv.z + bf2f(s4.z) + g * ((v.z - mean) * r * wv.z + bv.z);
  o.w = xv.w + bf2f(s4.w) + g * ((v.w - mean) * r * wv.w + bv.w);
  ((float4*)(x1 + base))[lane] = o;
}

// ---------------- MFMA spatial attention, one block per (frame, head) --------------
__global__ __launch_bounds__(256) void attn_mfma(const unsigned short* __restrict__ qkv,
                                                 const float* __restrict__ maskh,
                                                 unsigned short* __restrict__ o) {
  __shared__ unsigned short Qs[128 * 32];
  __shared__ unsigned short Ks[128 * 32];
  __shared__ unsigned short Vt[32 * 136];    // [d][f], padded
  __shared__ unsigned short Ps[128 * 136];   // [e][f], padded
  int tid = threadIdx.x, lane = tid & 63, wave = tid >> 6;
  int h = blockIdx.x & 7, bt = blockIdx.x >> 3;
  size_t gbase = (size_t)bt * 128 * 768 + h * 32;
#pragma unroll
  for (int i = 0; i < 2; ++i) {
    int q = wave * 2 + i;
    int row = q * 16 + (lane >> 2);
    int seg = (lane & 3) * 8;
    gload16(qkv + gbase + (size_t)row * 768 + seg, &Qs[q * 512]);
    gload16(qkv + gbase + 256 + (size_t)row * 768 + seg, &Ks[q * 512]);
  }
  {
    int e = tid >> 1, dh = (tid & 1) * 16;
    const unsigned short* gv = qkv + gbase + 512 + (size_t)e * 768 + dh;
    short8 v0 = *(const short8*)gv;
    short8 v1 = *(const short8*)(gv + 8);
#pragma unroll
    for (int j = 0; j < 8; ++j) {
      Vt[(dh + j) * 136 + e]     = (unsigned short)v0[j];
      Vt[(dh + 8 + j) * 136 + e] = (unsigned short)v1[j];
    }
  }
  __syncthreads();
  int arow = lane & 15, akk = (lane >> 4) * 8;
  int crow0 = (lane >> 4) * 4, ccol = lane & 15;
  short8 af0 = *(const short8*)&Qs[(wave * 32 + arow) * 32 + akk];
  short8 af1 = *(const short8*)&Qs[(wave * 32 + 16 + arow) * 32 + akk];
#pragma unroll
  for (int j = 0; j < 8; ++j) {
    short8 bfr = *(const short8*)&Ks[(j * 16 + arow) * 32 + akk];
    f32x4 s0 = __builtin_amdgcn_mfma_f32_16x16x32_bf16(af0, bfr, (f32x4)(0.0f), 0, 0, 0);
    f32x4 s1 = __builtin_amdgcn_mfma_f32_16x16x32_bf16(af1, bfr, (f32x4)(0.0f), 0, 0, 0);
    int f = j * 16 + ccol;
#pragma unroll
    for (int r = 0; r < 4; ++r) {
      int e0 = wave * 32 + crow0 + r;
      int e1 = e0 + 16;
      Ps[e0 * 136 + f] = f2bf(maskh[e0 * 128 + f] * s0[r] + 0.5f);
      Ps[e1 * 136 + f] = f2bf(maskh[e1 * 128 + f] * s1[r] + 0.5f);
    }
  }
  f32x4 acc[2][2];
#pragma unroll
  for (int i = 0; i < 2; ++i)
#pragma unroll
    for (int j = 0; j < 2; ++j) acc[i][j] = (f32x4)(0.0f);
#pragma unroll
  for (int k0 = 0; k0 < 128; k0 += 32) {
    short8 a0 = *(const short8*)&Ps[(wave * 32 + arow) * 136 + k0 + akk];
    short8 a1 = *(const short8*)&Ps[(wave * 32 + 16 + arow) * 136 + k0 + akk];
    short8 b0 = *(const short8*)&Vt[arow * 136 + k0 + akk];
    short8 b1 = *(const short8*)&Vt[(16 + arow) * 136 + k0 + akk];
    acc[0][0] = __builtin_amdgcn_mfma_f32_16x16x32_bf16(a0, b0, acc[0][0], 0, 0, 0);
    acc[0][1] = __builtin_amdgcn_mfma_f32_16x16x32_bf16(a0, b1, acc[0][1], 0, 0, 0);
    acc[1][0] = __builtin_amdgcn_mfma_f32_16x16x32_bf16(a1, b0, acc[1][0], 0, 0, 0);
    acc[1][1] = __builtin_amdgcn_mfma_f32_16x16x32_bf16(a1, b1, acc[1][1], 0, 0, 0);
  }
  unsigned short* ob = o + (size_t)bt * 128 * 256 + h * 32;
#pragma unroll
  for (int i = 0; i < 2; ++i)
#pragma unroll
    for (int j = 0; j < 2; ++j)
#pragma unroll
      for (int r = 0; r < 4; ++r) {
        int e = wave * 32 + i * 16 + crow0 + r;
        ob[(size_t)e * 256 + j * 16 + ccol] = f2bf(acc[i][j][r]);
      }
}

// ---------------- prep kernels -----------------------------------------------------
__global__ __launch_bounds__(256) void transcast(const float* __restrict__ src,
                                                 unsigned short* __restrict__ dst,
                                                 int N, int K) {   // dst[n*K+k] = src[k*N+n]
  int idx = blockIdx.x * 256 + threadIdx.x;
  int n = idx / K, k = idx - n * K;
  dst[idx] = f2bf(src[(size_t)k * N + n]);
}
__global__ __launch_bounds__(256) void castbf(const float* __restrict__ s,
                                              unsigned short* __restrict__ d) {
  int i = blockIdx.x * 256 + threadIdx.x;
  d[i] = f2bf(s[i]);
}
__global__ __launch_bounds__(256) void pack_conv1(const float* __restrict__ w1,
                                                  unsigned short* __restrict__ dst) {
  int idx = blockIdx.x * 256 + threadIdx.x;   // 512*768: [h][slab*256+c]
  int hh = idx / 768, kk = idx - hh * 768;
  int slab = kk >> 8, c = kk & 255;
  dst[idx] = f2bf(w1[(size_t)hh * 768 + c * 3 + slab]);
}
__global__ __launch_bounds__(256) void bnfold(const float* __restrict__ w,
                                              const float* __restrict__ bvec,
                                              const float* __restrict__ m,
                                              const float* __restrict__ v,
                                              float* __restrict__ s,
                                              float* __restrict__ o, int n) {
  int i = blockIdx.x * 256 + threadIdx.x;
  if (i < n) {
    float sc = w[i] * rsqrtf(v[i] + EPSF);
    s[i] = sc;
    o[i] = bvec[i] - m[i] * sc;
  }
}
__global__ __launch_bounds__(256) void mask_prep(const int* __restrict__ adj,
                                                 float* __restrict__ maskh) {
  int i = blockIdx.x * 256 + threadIdx.x;   // 16384
  maskh[i] = 0.5f * (float)adj[i];
}
__global__ __launch_bounds__(256) void zero_pad(unsigned short* __restrict__ xt) {
  int idx = blockIdx.x * 256 + threadIdx.x;   // 8 b * 2 rows * 128*256
  int bb = idx >> 16;
  int rem = idx & 65535;
  int which = rem >> 15;      // 0 -> t_pad 0, 1 -> t_pad 65
  int off = rem & 32767;
  size_t base = ((size_t)(bb * 66 + which * 65)) * 128 * 256;
  xt[base + off] = 0;
}

// ---------------- host-side launch --------------------------------------------------
extern "C" void kernel_launch(void* const* d_in, const int* in_sizes, int n_in,
                              void* d_out, int out_size, void* d_ws, size_t ws_size,
                              hipStream_t stream) {
  (void)in_sizes; (void)n_in; (void)out_size; (void)ws_size;
  const float* x       = (const float*)d_in[0];
  const int*   adj     = (const int*)  d_in[1];
  const float* n1_w    = (const float*)d_in[2];
  const float* n1_b    = (const float*)d_in[3];
  const float* q_w     = (const float*)d_in[4];
  const float* k_w     = (const float*)d_in[5];
  const float* v_w     = (const float*)d_in[6];
  const float* proj_w  = (const float*)d_in[7];
  const float* proj_b  = (const float*)d_in[8];
  const float* on_w    = (const float*)d_in[9];
  const float* on_b    = (const float*)d_in[10];
  const float* gamma_s = (const float*)d_in[11];
  const float* conv1_w = (const float*)d_in[12];
  const float* bn1_w   = (const float*)d_in[13];
  const float* bn1_b   = (const float*)d_in[14];
  const float* bn1_m   = (const float*)d_in[15];
  const float* bn1_v   = (const float*)d_in[16];
  const float* conv2_w = (const float*)d_in[17];
  const float* bn2_w   = (const float*)d_in[18];
  const float* bn2_b   = (const float*)d_in[19];
  const float* bn2_m   = (const float*)d_in[20];
  const float* bn2_v   = (const float*)d_in[21];
  const float* tn_w    = (const float*)d_in[22];
  const float* tn_b    = (const float*)d_in[23];
  const float* gamma_t = (const float*)d_in[24];
  const float* n3_w    = (const float*)d_in[25];
  const float* n3_b    = (const float*)d_in[26];
  const float* fc1_w   = (const float*)d_in[27];
  const float* fc1_b   = (const float*)d_in[28];
  const float* fc2_w   = (const float*)d_in[29];
  const float* fc2_b   = (const float*)d_in[30];
  float* O = (float*)d_out;

  const size_t MB = 1024 * 1024;
  char* wsb = (char*)d_ws;
  // live-range overlaid buffers (peak ~170 MB)
  unsigned short* qkvb = (unsigned short*)(wsb + 0);        // 96 MB  [qkv gemm -> attn]
  float*          pjo  = (float*)(wsb + 0);                 // 64 MB  [proj out f32]
  float*          x1b  = (float*)(wsb + 0);                 // 64 MB  [ln_resid -> conv2] (aliases pjo, in-place)
  unsigned short* xmb  = (unsigned short*)(wsb + 0);        // 32 MB  [ln3 -> fc1]
  unsigned short* hb   = (unsigned short*)(wsb + 32 * MB);  // 128 MB [fc1 -> fc2]
  unsigned short* xtp  = (unsigned short*)(wsb + 64 * MB);  // 33 MB  [ln_t -> conv1]
  unsigned short* xsb  = (unsigned short*)(wsb + 96 * MB);  // 32 MB  [ln1 -> ln_resid]
  unsigned short* oat  = (unsigned short*)(wsb + 128 * MB); // 32 MB  [attn -> proj]
  unsigned short* y1b  = (unsigned short*)(wsb + 100 * MB); // 64 MB  [conv1 -> conv2]
  char* wp = wsb + 164 * MB;
  unsigned short* Wqkv = (unsigned short*)wp;  wp += 768 * 256 * 2;
  unsigned short* PjT  = (unsigned short*)wp;  wp += 256 * 256 * 2;
  unsigned short* W1t  = (unsigned short*)wp;  wp += 512 * 768 * 2;
  unsigned short* W2t  = (unsigned short*)wp;  wp += 256 * 512 * 2;
  unsigned short* F1t  = (unsigned short*)wp;  wp += 1024 * 256 * 2;
  unsigned short* F2t  = (unsigned short*)wp;  wp += 256 * 1024 * 2;
  float* s1 = (float*)wp; wp += 512 * 4;
  float* o1 = (float*)wp; wp += 512 * 4;
  float* s2 = (float*)wp; wp += 256 * 4;
  float* o2 = (float*)wp; wp += 256 * 4;
  float* maskh = (float*)wp; wp += 16384 * 4;

  // ---- prep (cheap, once per launch) ----
  transcast<<<768 * 256 / 256, 256, 0, stream>>>(q_w, Wqkv, 256, 256);
  transcast<<<768 * 256 / 256, 256, 0, stream>>>(k_w, Wqkv + 256 * 256, 256, 256);
  transcast<<<768 * 256 / 256, 256, 0, stream>>>(v_w, Wqkv + 512 * 256, 256, 256);
  transcast<<<256 * 256 / 256, 256, 0, stream>>>(proj_w, PjT, 256, 256);
  pack_conv1<<<512 * 768 / 256, 256, 0, stream>>>(conv1_w, W1t);
  castbf<<<256 * 512 / 256, 256, 0, stream>>>(conv2_w, W2t);   // already [C][H] = [N][K]
  transcast<<<1024 * 256 / 256, 256, 0, stream>>>(fc1_w, F1t, 1024, 256);
  transcast<<<256 * 1024 / 256, 256, 0, stream>>>(fc2_w, F2t, 256, 1024);
  bnfold<<<2, 256, 0, stream>>>(bn1_w, bn1_b, bn1_m, bn1_v, s1, o1, 512);
  bnfold<<<1, 256, 0, stream>>>(bn2_w, bn2_b, bn2_m, bn2_v, s2, o2, 256);
  mask_prep<<<64, 256, 0, stream>>>(adj, maskh);
  zero_pad<<<524288 / 256, 256, 0, stream>>>(xtp);

  // ---- spatial attention branch ----
  ln256_bf<false><<<NTOK / 4, 256, 0, stream>>>(x, n1_w, n1_b, xsb);
  mfma_gemm<0, false, 256, 768><<<dim3(3, 256), 512, 0, stream>>>(xsb, Wqkv, nullptr, nullptr, nullptr, nullptr, qkvb);
  attn_mfma<<<Bn * Tn * NHd, 256, 0, stream>>>(qkvb, maskh, oat);
  mfma_gemm<5, false, 256, 256><<<dim3(1, 256), 512, 0, stream>>>(oat, PjT, nullptr, proj_b, nullptr, nullptr, pjo);
  ln_resid<<<NTOK / 4, 256, 0, stream>>>(pjo, on_w, on_b, x, xsb, gamma_s, x1b);

  // ---- temporal conv branch ----
  ln256_bf<true><<<NTOK / 4, 256, 0, stream>>>(x1b, tn_w, tn_b, xtp);
  mfma_gemm<2, true, 768, 512><<<dim3(2, 256), 512, 0, stream>>>(xtp, W1t, s1, o1, nullptr, nullptr, y1b);
  mfma_gemm<3, false, 512, 256><<<dim3(1, 256), 512, 0, stream>>>(y1b, W2t, s2, o2, x1b, gamma_t, O);

  // ---- MLP ----
  ln256_bf<false><<<NTOK / 4, 256, 0, stream>>>(O, n3_w, n3_b, xmb);
  mfma_gemm<2, false, 256, 1024><<<dim3(4, 256), 512, 0, stream>>>(xmb, F1t, nullptr, fc1_b, nullptr, nullptr, hb);
  mfma_gemm<4, false, 1024, 256><<<dim3(1, 256), 512, 0, stream>>>(hb, F2t, nullptr, fc2_b, O, nullptr, O);
}